// Round 11
// baseline (228.840 us; speedup 1.0000x reference)
//
#include <hip/hip_runtime.h>
#include <hip/hip_bf16.h>
#include <math.h>

// Problem constants
constexpr int Dd = 64, Hh = 64, Ww = 64;
constexpr int DHW = Dd * Hh * Ww;   // 262144
constexpr int HW = Hh * Ww;         // 4096
constexpr int XT_S = 128 * 128;     // XrayT spatial
constexpr int XP_S = 130 * 130;     // padded xray spatial

using short8 = __attribute__((ext_vector_type(8))) short;
using f32x4  = __attribute__((ext_vector_type(4))) float;

struct Geom {
    double s0, s1, s2;
    double c0ms0;
    double tmin1, tmax1, tmin2, tmax2;
    double d1, d2;
};

__device__ __forceinline__ void xray_coord(const Geom g, int z, int x, int y,
                                           float& py, float& px) {
    double wgt = g.c0ms0 / ((double)z - g.s0);
    double X1 = wgt * ((double)x - g.s1) + g.s1;
    X1 = fmin(fmax(X1, g.tmin1), g.tmax1);
    double X2 = wgt * ((double)y - g.s2) + g.s2;
    X2 = fmin(fmax(X2, g.tmin2), g.tmax2);
    py = (float)((X1 - g.tmin1) / g.d1);
    px = (float)((X2 - g.tmin2) / g.d2);
}

__device__ __forceinline__ float bf2f(unsigned short u) {
    union { unsigned int i; float f; } v;
    v.i = ((unsigned int)u) << 16;
    return v.f;
}
__device__ __forceinline__ unsigned short f2bf(float f) {
    __hip_bfloat16 h = __float2bfloat16(f);
    return *reinterpret_cast<unsigned short*>(&h);
}

// ---------- weight prep: wB[s][lane][j] bf16 in MFMA B-frag order ------------
template <int CIN, int NK>
__global__ __launch_bounds__(256) void k_wprep(const float* __restrict__ w6,
                                               const float* __restrict__ w3,
                                               unsigned short* __restrict__ wB) {
    int i = blockIdx.x * 256 + threadIdx.x;
    if (i >= NK * 64 * 8) return;
    int s = i >> 9, l = (i >> 3) & 63, j = i & 7;
    int n = l & 15, q = l >> 4;
    int k = s * 32 + q * 8 + j;
    int tap = k / CIN, ci = k % CIN;
    float v = 0.f;
    if (tap < 27) {
        if (w3 == nullptr) {
            v = w6[(n * CIN + ci) * 27 + tap];
        } else {
            if (n < 6) v = w6[(n * CIN + ci) * 27 + tap];
            else if (n < 9) v = w3[((n - 6) * CIN + ci) * 27 + tap];
        }
    }
    wB[i] = f2bf(v);
}

__global__ void k_bias9(const float* __restrict__ pb, const float* __restrict__ mb,
                        float* __restrict__ b9) {
    int i = threadIdx.x;
    if (i < 16) b9[i] = (i < 6) ? pb[i] : ((i < 9) ? mb[i - 6] : 0.f);
}

// ---------- Xray transposes (channels-last bf16) -----------------------------
__global__ __launch_bounds__(256) void k_xrayT(const float* __restrict__ X,
                                               unsigned short* __restrict__ XT) {
    int i = blockIdx.x * 256 + threadIdx.x;
    if (i >= 2 * XT_S) return;
    int b = i / XT_S, sp = i % XT_S;
    const float* src = X + (size_t)b * 16 * XT_S + sp;
    unsigned short* o = XT + (size_t)i * 16;
#pragma unroll
    for (int c = 0; c < 16; ++c) o[c] = f2bf(src[(size_t)c * XT_S]);
}

__global__ __launch_bounds__(256) void k_xpT(const float* __restrict__ X,
                                             unsigned short* __restrict__ XP) {
    int i = blockIdx.x * 256 + threadIdx.x;
    if (i >= 2 * XP_S) return;
    int b = i / XP_S, rc = i % XP_S;
    int r = rc / 130, c = rc % 130;
    unsigned short o[16];
    if (r >= 1 && r <= 128 && c >= 1 && c <= 128) {
        const float* src = X + (size_t)b * 16 * XT_S + (r - 1) * 128 + (c - 1);
#pragma unroll
        for (int ch = 0; ch < 16; ++ch) o[ch] = f2bf(src[(size_t)ch * XT_S]);
    } else {
#pragma unroll
        for (int ch = 0; ch < 16; ++ch) o[ch] = 0;
    }
    uint4* dst = (uint4*)(XP + (size_t)i * 16);
    uint4* s4 = (uint4*)o;
    dst[0] = s4[0]; dst[1] = s4[1];
}

// ---------- fill nin (unpadded [B][DHW][32]): ch0-15 = CT, ch16-31 = xi ------
__global__ __launch_bounds__(256) void k_prep_nin(const float* __restrict__ CT,
                                                  const unsigned short* __restrict__ XT,
                                                  unsigned short* __restrict__ nin,
                                                  Geom g) {
    int vox = blockIdx.x * 256 + threadIdx.x;
    int b = blockIdx.y;
    int z = vox >> 12, x = (vox >> 6) & 63, y = vox & 63;
    unsigned short outv[32];
    const float* ct = CT + (size_t)b * 16 * DHW + vox;
#pragma unroll
    for (int c = 0; c < 16; ++c) outv[c] = f2bf(ct[(size_t)c * DHW]);
    float py, px;
    xray_coord(g, z, x, y, py, px);
    float fy = floorf(py), fx = floorf(px);
    int y0 = (int)fminf(fmaxf(fy, 0.f), 127.f);
    int y1 = (int)fminf(fmaxf(fy + 1.f, 0.f), 127.f);
    int x0 = (int)fminf(fmaxf(fx, 0.f), 127.f);
    int x1 = (int)fminf(fmaxf(fx + 1.f, 0.f), 127.f);
    float y0f = (float)y0, y1f = (float)y1, x0f = (float)x0, x1f = (float)x1;
    float glt = (1.f + (y0f - py)) * (1.f + (x0f - px));
    float grb = (1.f - (y1f - py)) * (1.f - (x1f - px));
    float grt = (1.f + (y0f - py)) * (1.f - (x1f - px));
    float glb = (1.f - (y1f - py)) * (1.f + (x0f - px));
    const unsigned short* base = XT + (size_t)b * XT_S * 16;
    const unsigned short* p00 = base + (size_t)(y0 * 128 + x0) * 16;
    const unsigned short* p11 = base + (size_t)(y1 * 128 + x1) * 16;
    const unsigned short* p01 = base + (size_t)(y0 * 128 + x1) * 16;
    const unsigned short* p10 = base + (size_t)(y1 * 128 + x0) * 16;
#pragma unroll
    for (int c = 0; c < 16; ++c) {
        float v = glt * bf2f(p00[c]) + grb * bf2f(p11[c]) +
                  grt * bf2f(p01[c]) + glb * bf2f(p10[c]);
        outv[16 + c] = f2bf(v);
    }
    uint4* dst = (uint4*)(nin + ((size_t)b * DHW + vox) * 32);
    uint4* s4 = (uint4*)outv;
    dst[0] = s4[0]; dst[1] = s4[1]; dst[2] = s4[2]; dst[3] = s4[3];
}

// ---------- fused conv9 (32->16 MFMA) + softmax + p_coor + deform gather -----
// Tile: 4z x 2x x 16y (LDS 27.6 KB -> ~5 blocks/CU). Writes xs + pcoor.
__global__ __launch_bounds__(256) void k_conv9_deform(
    const unsigned short* __restrict__ IN, const unsigned short* __restrict__ wB,
    const float* __restrict__ bias, const unsigned short* __restrict__ XP,
    unsigned short* __restrict__ xs, float* __restrict__ pcoor, Geom g) {
    __shared__ char smem[4 * 432 * 8 * 2];   // 27648 B: staging, then ptile alias
    unsigned short* lds = (unsigned short*)smem;
    float* ptile = (float*)smem;             // [128][17] = 8704 B

    int tid = threadIdx.x;
    int bid = blockIdx.x;
    int zt = bid & 15, xt = (bid >> 4) & 31, yt = bid >> 9;
    int b = blockIdx.y;

    // stage 6z x 4x x 18y region x 32ch, bounds-checked (zero outside volume)
    const unsigned short* gsrc = IN + (size_t)b * DHW * 32;
    for (int d = tid; d < 4 * 432; d += 256) {
        int slot = d & 3;
        int sp = d >> 2;
        int zz = sp / 72;
        int rem = sp - zz * 72;
        int xx = rem / 18, yy = rem - xx * 18;
        int gz = zt * 4 + zz - 1, gx = xt * 2 + xx - 1, gy = yt * 16 + yy - 1;
        uint4 v = {0u, 0u, 0u, 0u};
        if ((unsigned)gz < 64u && (unsigned)gx < 64u && (unsigned)gy < 64u) {
            size_t gp = (size_t)gz * HW + gx * 64 + gy;
            v = *(const uint4*)(gsrc + gp * 32 + slot * 8);
        }
        *(uint4*)&lds[(size_t)(slot * 432 + sp) * 8] = v;
    }

    int lane = tid & 63;
    short8 bw[27];
    {
        const short8* wsrc = (const short8*)wB;
#pragma unroll
        for (int s = 0; s < 27; ++s) bw[s] = wsrc[s * 64 + lane];
    }
    int col = lane & 15, q = lane >> 4;
    float bcol = bias[col];
    __syncthreads();

    int w = tid >> 6;
    float accs[2][4];
    for (int vx = 0; vx < 2; ++vx) {
        f32x4 acc = {0.f, 0.f, 0.f, 0.f};
#pragma unroll
        for (int s = 0; s < 27; ++s) {
            int slot = q & 3;
            int dz = s / 9;
            int trem = s - dz * 9;
            int dx = trem / 3, dy = trem - dx * 3;
            int addr = ((slot * 432) + (w + dz) * 72 + (vx + dx) * 18 + col + dy) * 8;
            short8 a = *(const short8*)&lds[addr];
            acc = __builtin_amdgcn_mfma_f32_16x16x32_bf16(a, bw[s], acc, 0, 0, 0);
        }
#pragma unroll
        for (int r = 0; r < 4; ++r) accs[vx][r] = acc[r] + bcol;
    }
    __syncthreads();  // all MFMA LDS reads done; safe to overwrite with ptile
#pragma unroll
    for (int vx = 0; vx < 2; ++vx)
#pragma unroll
        for (int r = 0; r < 4; ++r)
            ptile[(w * 32 + vx * 16 + q * 4 + r) * 17 + col] = accs[vx][r];
    __syncthreads();

    // per-thread deform for local voxel t = tid (128 voxels in tile)
    if (tid < 128) {
        int z = zt * 4 + (tid >> 5);
        int x = xt * 2 + ((tid >> 4) & 1);
        int y = yt * 16 + (tid & 15);
        int vox = z * HW + x * 64 + y;
        const float* pt = &ptile[tid * 17];
        float bpy, bpx;
        xray_coord(g, z, x, y, bpy, bpx);
        float off0 = pt[0], off1 = pt[1], off2 = pt[2];
        float off3 = pt[3], off4 = pt[4], off5 = pt[5];
        float mv0 = pt[6], mv1 = pt[7], mv2 = pt[8];
        float mx = fmaxf(mv0, fmaxf(mv1, mv2));
        float e0 = __expf(mv0 - mx), e1 = __expf(mv1 - mx), e2 = __expf(mv2 - mx);
        float inv = 1.f / (e0 + e1 + e2);
        float ms[3] = {e0 * inv, e1 * inv, e2 * inv};

        float pys[3], pxs3[3];
        pys[0] = fminf(fmaxf(off0 + bpy + 1.f, 0.f), 129.f);
        pys[1] = fminf(fmaxf(off1 + bpy + 1.f, 0.f), 129.f);
        pys[2] = fminf(fmaxf(off2 + bpy + 1.f, 0.f), 129.f);
        pxs3[0] = fminf(fmaxf(off3 + bpx + 1.f, 0.f), 129.f);
        pxs3[1] = fminf(fmaxf(off4 + bpx + 1.f, 0.f), 129.f);
        pxs3[2] = fminf(fmaxf(off5 + bpx + 1.f, 0.f), 129.f);
        float* pc = pcoor + ((size_t)b * DHW + vox) * 6;
        pc[0] = pys[0]; pc[1] = pys[1]; pc[2] = pys[2];
        pc[3] = pxs3[0]; pc[4] = pxs3[1]; pc[5] = pxs3[2];

        float acc16[16];
#pragma unroll
        for (int c = 0; c < 16; ++c) acc16[c] = 0.f;
        const unsigned short* xpb = XP + (size_t)b * XP_S * 16;
#pragma unroll
        for (int p = 0; p < 3; ++p) {
            float py = pys[p], px = pxs3[p];
            float fy = floorf(py), fx = floorf(px);
            int y0 = (int)fminf(fmaxf(fy, 0.f), 129.f);
            int y1 = (int)fminf(fmaxf(fy + 1.f, 0.f), 129.f);
            int x0 = (int)fminf(fmaxf(fx, 0.f), 129.f);
            int x1 = (int)fminf(fmaxf(fx + 1.f, 0.f), 129.f);
            float y0f = (float)y0, y1f = (float)y1, x0f = (float)x0, x1f = (float)x1;
            float glt = (1.f + (y0f - py)) * (1.f + (x0f - px));
            float grb = (1.f - (y1f - py)) * (1.f - (x1f - px));
            float grt = (1.f + (y0f - py)) * (1.f - (x1f - px));
            float glb = (1.f - (y1f - py)) * (1.f + (x0f - px));
            const unsigned short* p00 = xpb + (size_t)(y0 * 130 + x0) * 16;
            const unsigned short* p11 = xpb + (size_t)(y1 * 130 + x1) * 16;
            const unsigned short* p01 = xpb + (size_t)(y0 * 130 + x1) * 16;
            const unsigned short* p10 = xpb + (size_t)(y1 * 130 + x0) * 16;
            float mp = ms[p];
#pragma unroll
            for (int c = 0; c < 16; ++c) {
                float v = glt * bf2f(p00[c]) + grb * bf2f(p11[c]) +
                          grt * bf2f(p01[c]) + glb * bf2f(p10[c]);
                acc16[c] += mp * v;
            }
        }
        unsigned short outv[16];
#pragma unroll
        for (int c = 0; c < 16; ++c) outv[c] = f2bf(acc16[c]);
        uint4* dst = (uint4*)(xs + ((size_t)b * DHW + vox) * 16);
        uint4* s4 = (uint4*)outv;
        dst[0] = s4[0]; dst[1] = s4[1];
    }
}

// ---------- MFMA implicit-GEMM conv (unpadded, bounds-checked staging) -------
// TX = x-tile width (2 or 4). Tile: 4z x TXx x 16y.
// MODE 1: CIN=32 dual-src (nin ch0-15 + xs), +bias, BN, leaky -> nh bf16 [B][DHW][16]
// MODE 2: CIN=16 single-src nh, +bias -> out0 fp32 NCDHW
template <int CIN, int NK, int MODE, int TX>
__global__ __launch_bounds__(256) void k_conv_mfma(
    const unsigned short* __restrict__ IN, const unsigned short* __restrict__ IN2,
    const unsigned short* __restrict__ wB, const float* __restrict__ bias,
    const float* __restrict__ bng, const float* __restrict__ bnb,
    const float* __restrict__ bnm, const float* __restrict__ bnv,
    float* __restrict__ outF, unsigned short* __restrict__ outH) {
    constexpr int NSLOT = CIN / 8;
    constexpr int XREG = TX + 2;
    constexpr int REG = 6 * XREG * 18;
    constexpr int NCHUNK = NSLOT * REG;
    constexpr int XT_N = 64 / TX;
    __shared__ unsigned short lds[NSLOT * REG * 8];

    int tid = threadIdx.x;
    int bid = blockIdx.x;
    int zt = bid & 15, xt = (bid >> 4) & (XT_N - 1);
    int yt = bid >> ((TX == 2) ? 9 : 8);
    int b = blockIdx.y;

    const unsigned short* src1 = IN + (size_t)b * DHW * ((MODE == 1) ? 32 : 16);
    const unsigned short* src2 =
        (MODE == 1) ? (IN2 + (size_t)b * DHW * 16) : nullptr;
    for (int d = tid; d < NCHUNK; d += 256) {
        int slot = d & (NSLOT - 1);
        int sp = d / NSLOT;
        int zz = sp / (XREG * 18);
        int rem = sp - zz * (XREG * 18);
        int xx = rem / 18, yy = rem - xx * 18;
        int gz = zt * 4 + zz - 1, gx = xt * TX + xx - 1, gy = yt * 16 + yy - 1;
        uint4 v = {0u, 0u, 0u, 0u};
        if ((unsigned)gz < 64u && (unsigned)gx < 64u && (unsigned)gy < 64u) {
            size_t gp = (size_t)gz * HW + gx * 64 + gy;
            if (MODE == 1) {
                if (slot < 2) v = *(const uint4*)(src1 + gp * 32 + slot * 8);
                else v = *(const uint4*)(src2 + gp * 16 + (slot - 2) * 8);
            } else {
                v = *(const uint4*)(src1 + gp * 16 + slot * 8);
            }
        }
        *(uint4*)&lds[(size_t)(slot * REG + sp) * 8] = v;
    }

    int lane = tid & 63;
    short8 bw[NK];
    {
        const short8* wsrc = (const short8*)wB;
#pragma unroll
        for (int s = 0; s < NK; ++s) bw[s] = wsrc[s * 64 + lane];
    }
    int col = lane & 15, q = lane >> 4;
    float bcol = bias[col];
    float bsc = 1.f, bsh = 0.f;
    if (MODE == 1) {
        float sc = bng[col] * rsqrtf(bnv[col] + 1e-5f);
        bsc = sc;
        bsh = bnb[col] - bnm[col] * sc;
    }
    __syncthreads();

    int w = tid >> 6;
    for (int vx = 0; vx < TX; ++vx) {
        f32x4 acc = {0.f, 0.f, 0.f, 0.f};
#pragma unroll
        for (int s = 0; s < NK; ++s) {
            int tap = (s * 32 + q * 8) / CIN;
            if (CIN == 16) tap = min(tap, 26);  // K-pad: weights zero there
            int slot = q & (NSLOT - 1);
            int dz = tap / 9;
            int trem = tap - dz * 9;
            int dx = trem / 3, dy = trem - dx * 3;
            int addr = ((slot * REG) + (w + dz) * (XREG * 18) + (vx + dx) * 18 +
                        col + dy) * 8;
            short8 a = *(const short8*)&lds[addr];
            acc = __builtin_amdgcn_mfma_f32_16x16x32_bf16(a, bw[s], acc, 0, 0, 0);
        }
        int z = zt * 4 + w, x = xt * TX + vx;
        int yb = yt * 16 + q * 4;
        int vox = z * HW + x * 64 + yb;
        if (MODE == 1) {
            unsigned short* o = outH + ((size_t)b * DHW + vox) * 16 + col;
#pragma unroll
            for (int r = 0; r < 4; ++r) {
                float v = acc[r] + bcol;
                v = v * bsc + bsh;
                v = (v >= 0.f) ? v : 0.2f * v;
                o[(size_t)r * 16] = f2bf(v);
            }
        } else {
            float* o = outF + ((size_t)b * 16 + col) * DHW + vox;
#pragma unroll
            for (int r = 0; r < 4; ++r) o[r] = acc[r] + bcol;
        }
    }
}

static void compute_geom(Geom& g) {
    const double sdr = 200.0, del = 2.0;
    double theta = M_PI, phi = 0.0, gam = M_PI / 2;
    double Rz[3][3] = {{cos(theta), -sin(theta), 0}, {sin(theta), cos(theta), 0}, {0, 0, 1}};
    double Ry[3][3] = {{cos(phi), 0, sin(phi)}, {0, 1, 0}, {-sin(phi), 0, cos(phi)}};
    double Rx[3][3] = {{1, 0, 0}, {0, cos(gam), -sin(gam)}, {0, sin(gam), cos(gam)}};
    double M[3][3], R[3][3];
    for (int i = 0; i < 3; i++)
        for (int j = 0; j < 3; j++) {
            double s = 0;
            for (int k = 0; k < 3; k++) s += Rz[i][k] * Ry[k][j];
            M[i][j] = s;
        }
    for (int i = 0; i < 3; i++)
        for (int j = 0; j < 3; j++) {
            double s = 0;
            for (int k = 0; k < 3; k++) s += M[i][k] * Rx[k][j];
            R[i][j] = sdr * s;
        }
    double trans[3] = {32.0, 32.0, 32.0};
    double src[3], ctr[3];
    for (int k = 0; k < 3; k++) {
        src[k] = R[k][0] + trans[k];
        ctr[k] = -R[k][0] + trans[k];
    }
    double Rn[3][3];
    for (int i = 0; i < 3; i++) {
        double n = sqrt(R[i][0] * R[i][0] + R[i][1] * R[i][1] + R[i][2] * R[i][2]);
        for (int j = 0; j < 3; j++) Rn[i][j] = R[i][j] / n;
    }
    double u[3], v[3];
    for (int k = 0; k < 3; k++) { u[k] = Rn[k][1]; v[k] = Rn[k][2]; }
    double tmin[3], tmax[3];
    for (int k = 0; k < 3; k++) {
        double a = 127.0 * fabs(u[k]) + 127.0 * fabs(v[k]);
        tmin[k] = ctr[k] - a;
        tmax[k] = ctr[k] + a;
    }
    double delta[3];
    for (int k = 0; k < 3; k++) delta[k] = del * u[k] + del * v[k];
    g.s0 = src[0]; g.s1 = src[1]; g.s2 = src[2];
    g.c0ms0 = ctr[0] - src[0];
    g.tmin1 = tmin[1]; g.tmax1 = tmax[1];
    g.tmin2 = tmin[2]; g.tmax2 = tmax[2];
    g.d1 = delta[1]; g.d2 = delta[2];
}

// workspace layout (bytes)
constexpr size_t NIN_B = (size_t)2 * DHW * 32 * 2;   // 33,554,432
constexpr size_t XS_B  = (size_t)2 * DHW * 16 * 2;   // 16,777,216
constexpr size_t NH_B  = XS_B;                       // 16,777,216
constexpr size_t XT_B  = (size_t)2 * XT_S * 16 * 2;  // 1,048,576
constexpr size_t XP_B  = (size_t)2 * XP_S * 16 * 2;  // 1,081,600
constexpr size_t WB9_B = (size_t)27 * 64 * 8 * 2;    // 27,648
constexpr size_t WB1_B = WB9_B;
constexpr size_t WB2_B = (size_t)14 * 64 * 8 * 2;    // 14,336

constexpr size_t O_NIN = 0;
constexpr size_t O_XS  = O_NIN + NIN_B;
constexpr size_t O_NH  = O_XS + XS_B;
constexpr size_t O_XT  = O_NH + NH_B;
constexpr size_t O_XP  = O_XT + XT_B;
constexpr size_t O_WB9 = O_XP + XP_B;
constexpr size_t O_WB1 = O_WB9 + WB9_B;
constexpr size_t O_WB2 = O_WB1 + WB1_B;
constexpr size_t O_B9  = O_WB2 + WB2_B;

extern "C" void kernel_launch(void* const* d_in, const int* in_sizes, int n_in,
                              void* d_out, int out_size, void* d_ws, size_t ws_size,
                              hipStream_t stream) {
    (void)in_sizes; (void)n_in; (void)out_size; (void)ws_size;
    const float* CT = (const float*)d_in[0];
    const float* Xray = (const float*)d_in[1];
    const float* pW = (const float*)d_in[2];
    const float* pb = (const float*)d_in[3];
    const float* mW = (const float*)d_in[4];
    const float* mb = (const float*)d_in[5];
    const float* w1 = (const float*)d_in[6];
    const float* b1 = (const float*)d_in[7];
    const float* w2 = (const float*)d_in[8];
    const float* b2 = (const float*)d_in[9];
    const float* bng = (const float*)d_in[10];
    const float* bnb = (const float*)d_in[11];
    const float* bnm = (const float*)d_in[12];
    const float* bnv = (const float*)d_in[13];

    char* ws = (char*)d_ws;
    unsigned short* nin = (unsigned short*)(ws + O_NIN);
    unsigned short* xs  = (unsigned short*)(ws + O_XS);
    unsigned short* nh  = (unsigned short*)(ws + O_NH);
    unsigned short* XT  = (unsigned short*)(ws + O_XT);
    unsigned short* XP  = (unsigned short*)(ws + O_XP);
    unsigned short* wB9 = (unsigned short*)(ws + O_WB9);
    unsigned short* wB1 = (unsigned short*)(ws + O_WB1);
    unsigned short* wB2 = (unsigned short*)(ws + O_WB2);
    float* b9 = (float*)(ws + O_B9);

    float* out0 = (float*)d_out;             // (2,16,64,64,64)
    float* out1 = out0 + (size_t)32 * DHW;   // (2,64,64,64,6)

    Geom g;
    compute_geom(g);

    // weight/bias prep
    k_wprep<32, 27><<<54, 256, 0, stream>>>(pW, mW, wB9);
    k_wprep<32, 27><<<54, 256, 0, stream>>>(w1, nullptr, wB1);
    k_wprep<16, 14><<<28, 256, 0, stream>>>(w2, nullptr, wB2);
    k_bias9<<<1, 64, 0, stream>>>(pb, mb, b9);

    // xray channels-last transposes
    k_xrayT<<<(2 * XT_S + 255) / 256, 256, 0, stream>>>(Xray, XT);
    k_xpT<<<(2 * XP_S + 255) / 256, 256, 0, stream>>>(Xray, XP);

    // nin: CT + xi (unpadded NDHWC)
    k_prep_nin<<<dim3(DHW / 256, 2), 256, 0, stream>>>(CT, XT, nin, g);

    // fused conv9 + softmax + p_coor + deform gather -> xs, out1 (TX=2 tile)
    k_conv9_deform<<<dim3(2048, 2), 256, 0, stream>>>(nin, wB9, b9, XP, xs, out1, g);

    // conv1 (nin ch0-15 + xs -> 16) + BN + leaky -> nh (TX=2 tile)
    k_conv_mfma<32, 27, 1, 2><<<dim3(2048, 2), 256, 0, stream>>>(
        nin, xs, wB1, b1, bng, bnb, bnm, bnv, nullptr, nh);

    // conv2 (16 -> 16) -> out0 (NCDHW fp32) (TX=4 tile)
    k_conv_mfma<16, 14, 2, 4><<<dim3(1024, 2), 256, 0, stream>>>(
        nh, nullptr, wB2, b2, nullptr, nullptr, nullptr, nullptr, out0, nullptr);
}